// Round 1
// baseline (26365.918 us; speedup 1.0000x reference)
//
#include <hip/hip_runtime.h>
#include <hip/hip_fp16.h>

// ---------------------------------------------------------------------------
// RNN chaotic scan, MI355X.
//   T=512, B=64, I=256, H=2048, O=64, alpha=0.1
// Plan:
//   prep kernels : stage Wi (hi/lo f16, MFMA B-frag layout), Wo (f16 frags),
//                  r(0) (hi/lo f16, MFMA A-frag layout)
//   pre_gemm     : pre = X @ Wi^T + bi  (split-f16 3-product MFMA, f32 out)
//                  written IN-PLACE into d_out's rate_all region
//   scan_kernel  : persistent, 256 WGs (1/CU). Wh tile in REGISTERS
//                  (hi/lo f16). Per step: MFMA partials -> f32 dumps ->
//                  reducer WG per h-slice: sum + pre + bh, tanh, leaky blend
//                  (f32 master state in regs), republish r hi/lo frags.
//                  Flag-based agent-scope sync, double-buffered (WAR-safe by
//                  transitive all-to-all dependency). Spin budget => no hang.
//   out_gemm     : out = rate_all @ Wo^T + bo (single f16 MFMA, HBM-bound)
// ---------------------------------------------------------------------------

typedef _Float16 f16;
typedef _Float16 f16x8 __attribute__((ext_vector_type(8)));
typedef float    f32x4 __attribute__((ext_vector_type(4)));

#define MFMA16(a, b, c) __builtin_amdgcn_mfma_f32_16x16x32_f16((a), (b), (c), 0, 0, 0)

#define OUT0_ELEMS  2097152   // T*B*O floats; rate_all follows in d_out
#define SPIN_BUDGET (1L << 22)

// ws layout (bytes)
#define WS_FLAGP 0            // 256 ints
#define WS_FLAGR 1024         // 32 ints
#define WS_RSTG  4096         // 4 planes x 131072 f16 (buf0 hi, buf0 lo, buf1 hi, buf1 lo)
#define WS_DUMP  (4096 + 1048576)            // 2*32*8*4096 f32 = 8 MB
#define WS_WI    (WS_DUMP + 8388608)         // hi 524288 f16, lo 524288 f16
#define WS_WO    (WS_WI + 2097152)           // 131072 f16

__device__ __forceinline__ void cvt_hilo8(const float4 p0, const float4 p1, f16x8& hi, f16x8& lo) {
    float v[8] = {p0.x, p0.y, p0.z, p0.w, p1.x, p1.y, p1.z, p1.w};
#pragma unroll
    for (int j = 0; j < 8; ++j) {
        f16 h = (f16)v[j];
        hi[j] = h;
        lo[j] = (f16)(v[j] - (float)h);
    }
}

__device__ __forceinline__ int ld_flag(int* p) {
    return __hip_atomic_load(p, __ATOMIC_RELAXED, __HIP_MEMORY_SCOPE_AGENT);
}
__device__ __forceinline__ void st_flag(int* p, int v) {
    __hip_atomic_store(p, v, __ATOMIC_RELAXED, __HIP_MEMORY_SCOPE_AGENT);
}
__device__ __forceinline__ void spin_ge(int* p, int target, long& budget) {
    while (budget > 0 && ld_flag(p) < target) {
        --budget;
        __builtin_amdgcn_s_sleep(2);
    }
}

// ------------------------------ prep kernels -------------------------------

__global__ void prep_wi(const float* __restrict__ Wi, f16* __restrict__ hi, f16* __restrict__ lo) {
    const int r    = blockIdx.x * 256 + threadIdx.x;    // [0, 65536)
    const int hblk = r >> 13, rem = r & 8191;
    const int kt = rem >> 10, rem2 = rem & 1023;
    const int nt = rem2 >> 6, lane = rem2 & 63;
    const int h = hblk * 256 + nt * 16 + (lane & 15);
    const int i = kt * 32 + (lane >> 4) * 8;
    const float* p = Wi + (long)h * 256 + i;
    float4 p0 = *(const float4*)p, p1 = *(const float4*)(p + 4);
    f16x8 vh, vl;
    cvt_hilo8(p0, p1, vh, vl);
    *(f16x8*)(hi + (long)r * 8) = vh;
    *(f16x8*)(lo + (long)r * 8) = vl;
}

__global__ void prep_wo(const float* __restrict__ Wo, f16* __restrict__ st) {
    const int r  = blockIdx.x * 256 + threadIdx.x;      // [0, 16384)
    const int nt = r >> 12, rem = r & 4095;
    const int kt = rem >> 6, lane = rem & 63;
    const int o = nt * 16 + (lane & 15);
    const int h = kt * 32 + (lane >> 4) * 8;
    const float* p = Wo + (long)o * 2048 + h;
    float4 p0 = *(const float4*)p, p1 = *(const float4*)(p + 4);
    float v[8] = {p0.x, p0.y, p0.z, p0.w, p1.x, p1.y, p1.z, p1.w};
    f16x8 a;
#pragma unroll
    for (int j = 0; j < 8; ++j) a[j] = (f16)v[j];
    *(f16x8*)(st + (long)r * 8) = a;
}

__global__ void prep_r0(const float* __restrict__ rate0, f16* __restrict__ hi, f16* __restrict__ lo) {
    const int r   = blockIdx.x * 256 + threadIdx.x;     // [0, 16384)
    const int ktg = r >> 8, rem = r & 255;
    const int mt = rem >> 6, lane = rem & 63;
    const int b = mt * 16 + (lane & 15);
    const int k = ktg * 32 + (lane >> 4) * 8;
    const float* p = rate0 + (long)b * 2048 + k;
    float4 p0 = *(const float4*)p, p1 = *(const float4*)(p + 4);
    f16x8 vh, vl;
    cvt_hilo8(p0, p1, vh, vl);
    *(f16x8*)(hi + (long)r * 8) = vh;
    *(f16x8*)(lo + (long)r * 8) = vl;
}

// ------------------------------- pre GEMM ----------------------------------
// pre[row][h] = X[row][:] . Wi[h][:] + bi[h]    row in [0, 32768), h in [0, 2048)

__global__ __launch_bounds__(256, 1) void pre_gemm(const float* __restrict__ X,
                                                   const f16* __restrict__ wih,
                                                   const f16* __restrict__ wil,
                                                   const float* __restrict__ bi,
                                                   float* __restrict__ pre) {
    const int wg = blockIdx.x;                 // 4096
    const int rowblk = wg >> 3, hblk = wg & 7; // hblk == XCD (L2 locality of Wi slice)
    const int tid = threadIdx.x, wv = tid >> 6, l = tid & 63;
    const int l15 = l & 15, lq = l >> 4;

    f16x8 Bh[8][4], Bl[8][4];  // 256 VGPR, persistent
#pragma unroll
    for (int kt = 0; kt < 8; ++kt)
#pragma unroll
        for (int nl = 0; nl < 4; ++nl) {
            const int  nt  = wv * 4 + nl;
            const long idx = (((long)(hblk * 8 + kt) * 16 + nt) * 64 + l) * 8;
            Bh[kt][nl] = *(const f16x8*)(wih + idx);
            Bl[kt][nl] = *(const f16x8*)(wil + idx);
        }
    float biv[4];
#pragma unroll
    for (int nl = 0; nl < 4; ++nl) biv[nl] = bi[hblk * 256 + (wv * 4 + nl) * 16 + l15];

#pragma unroll
    for (int mt = 0; mt < 4; ++mt) {
        const float* ap = X + (long)(rowblk * 64 + mt * 16 + l15) * 256 + lq * 8;
        f16x8 Ah[8], Al[8];
#pragma unroll
        for (int kt = 0; kt < 8; ++kt) {
            float4 p0 = *(const float4*)(ap + kt * 32);
            float4 p1 = *(const float4*)(ap + kt * 32 + 4);
            cvt_hilo8(p0, p1, Ah[kt], Al[kt]);
        }
        f32x4 acc[4] = {{0, 0, 0, 0}, {0, 0, 0, 0}, {0, 0, 0, 0}, {0, 0, 0, 0}};
#pragma unroll
        for (int kt = 0; kt < 8; ++kt)
#pragma unroll
            for (int nl = 0; nl < 4; ++nl) {
                acc[nl] = MFMA16(Al[kt], Bh[kt][nl], acc[nl]);
                acc[nl] = MFMA16(Ah[kt], Bl[kt][nl], acc[nl]);
                acc[nl] = MFMA16(Ah[kt], Bh[kt][nl], acc[nl]);
            }
#pragma unroll
        for (int nl = 0; nl < 4; ++nl)
#pragma unroll
            for (int q = 0; q < 4; ++q) {
                const int row = rowblk * 64 + mt * 16 + lq * 4 + q;
                const int h   = hblk * 256 + (wv * 4 + nl) * 16 + l15;
                pre[(long)row * 2048 + h] = acc[nl][q] + biv[nl];
            }
    }
}

// ------------------------------ scan kernel --------------------------------
// 256 WGs: hp = wg>>3 (h-slice of 64), s = wg&7 (k-shard of 256; == XCD).
// flagR[g] = t  <=> r_state(t) slice g published.  flagP[hp][s] = t+1 <=> partial(t) dumped.

__global__ __launch_bounds__(256, 1) void scan_kernel(const float* __restrict__ Wh,
                                                      const float* __restrict__ bhp,
                                                      const float* __restrict__ rate0,
                                                      float* __restrict__ ra,   // pre in, rate_all out (in-place)
                                                      f16* __restrict__ rh0, f16* __restrict__ rl0,
                                                      f16* __restrict__ rh1, f16* __restrict__ rl1,
                                                      float* __restrict__ dumps,
                                                      int* flagP, int* flagR) {
    const int wg = blockIdx.x;
    const int hp = wg >> 3, s = wg & 7;
    const int tid = threadIdx.x, wv = tid >> 6, l = tid & 63;
    const int l15 = l & 15, lq = l >> 4;
    const bool is_red = (s == (hp & 7));
    __shared__ float lds[64 * 68];

    // Wh tile -> registers (hi/lo f16 frags). 256 VGPR, lives across all steps.
    f16x8 WhH[8][4], WhL[8][4];
#pragma unroll
    for (int kt = 0; kt < 8; ++kt)
#pragma unroll
        for (int nt = 0; nt < 4; ++nt) {
            const float* p = Wh + (long)(hp * 64 + nt * 16 + l15) * 2048 + s * 256 + kt * 32 + lq * 8;
            float4 p0 = *(const float4*)p, p1 = *(const float4*)(p + 4);
            cvt_hilo8(p0, p1, WhH[kt][nt], WhL[kt][nt]);
        }

    float rf[4][4];  // f32 master state (reducers only), D-frag layout
    float bhv[4];
    if (is_red) {
#pragma unroll
        for (int nt = 0; nt < 4; ++nt) {
            bhv[nt] = bhp[hp * 64 + nt * 16 + l15];
#pragma unroll
            for (int q = 0; q < 4; ++q)
                rf[nt][q] = rate0[(long)(wv * 16 + lq * 4 + q) * 2048 + hp * 64 + nt * 16 + l15];
        }
    }

    long budget = SPIN_BUDGET;

    for (int t = 0; t < 512; ++t) {
        // prefetch pre[t] slice (reducers) - independent of flags, hides HBM latency
        float pr[4][4];
        if (is_red) {
#pragma unroll
            for (int nt = 0; nt < 4; ++nt)
#pragma unroll
                for (int q = 0; q < 4; ++q)
                    pr[nt][q] = ra[((long)t * 64 + wv * 16 + lq * 4 + q) * 2048 + hp * 64 + nt * 16 + l15];
        }

        const f16* rh = (t & 1) ? rh1 : rh0;
        const f16* rl = (t & 1) ? rl1 : rl0;
        f32x4 acc[4] = {{0, 0, 0, 0}, {0, 0, 0, 0}, {0, 0, 0, 0}, {0, 0, 0, 0}};

#pragma unroll
        for (int i = 0; i < 4; ++i) {  // consume r slices incrementally as they arrive
            spin_ge(flagR + 4 * s + i, t, budget);
            __builtin_amdgcn_fence(__ATOMIC_ACQUIRE, "agent");
#pragma unroll
            for (int kk = 0; kk < 2; ++kk) {
                const int  ktl = 2 * i + kk;
                const long idx = ((long)((s * 8 + ktl) * 4 + wv) * 64 + l) * 8;
                f16x8 ah = *(const f16x8*)(rh + idx);
                f16x8 al = *(const f16x8*)(rl + idx);
#pragma unroll
                for (int nt = 0; nt < 4; ++nt) {
                    acc[nt] = MFMA16(al, WhH[ktl][nt], acc[nt]);
                    acc[nt] = MFMA16(ah, WhL[ktl][nt], acc[nt]);
                    acc[nt] = MFMA16(ah, WhH[ktl][nt], acc[nt]);
                }
            }
        }

        // dump raw accumulator (layout-agnostic element correspondence across shards)
        float* dp = dumps + ((long)(t & 1) * 256 + hp * 8 + s) * 4096 + tid * 16;
#pragma unroll
        for (int nt = 0; nt < 4; ++nt) *(f32x4*)(dp + nt * 4) = acc[nt];
        __syncthreads();
        if (tid == 0) {
            __builtin_amdgcn_fence(__ATOMIC_RELEASE, "agent");
            st_flag(flagP + hp * 8 + s, t + 1);
        }

        if (is_red) {
            if (tid == 0) {
#pragma unroll
                for (int ss = 0; ss < 8; ++ss) spin_ge(flagP + hp * 8 + ss, t + 1, budget);
                __builtin_amdgcn_fence(__ATOMIC_ACQUIRE, "agent");
            }
            __syncthreads();

            float u[4][4] = {};
            const float* db = dumps + ((long)(t & 1) * 256 + hp * 8) * 4096 + tid * 16;
#pragma unroll
            for (int ss = 0; ss < 8; ++ss)
#pragma unroll
                for (int nt = 0; nt < 4; ++nt) {
                    f32x4 v = *(const f32x4*)(db + ss * 4096 + nt * 4);
                    u[nt][0] += v[0]; u[nt][1] += v[1]; u[nt][2] += v[2]; u[nt][3] += v[3];
                }
#pragma unroll
            for (int nt = 0; nt < 4; ++nt)
#pragma unroll
                for (int q = 0; q < 4; ++q) {
                    const float uu = u[nt][q] + pr[nt][q] + bhv[nt];
                    const float rn = tanhf(uu);
                    rf[nt][q] = 0.9f * rf[nt][q] + 0.1f * rn;
                    ra[((long)t * 64 + wv * 16 + lq * 4 + q) * 2048 + hp * 64 + nt * 16 + l15] = rf[nt][q];
                }

            // transpose D-frag -> A-frag layout via LDS, republish hi/lo f16
#pragma unroll
            for (int nt = 0; nt < 4; ++nt)
#pragma unroll
                for (int q = 0; q < 4; ++q)
                    lds[(wv * 16 + lq * 4 + q) * 68 + nt * 16 + l15] = rf[nt][q];
            __syncthreads();
            f16* wh_ = (t & 1) ? rh0 : rh1;  // buffer (t+1)&1
            f16* wl_ = (t & 1) ? rl0 : rl1;
#pragma unroll
            for (int i2 = 0; i2 < 2; ++i2) {
                const int c = tid + i2 * 256;
                const int b = c & 63, h8 = c >> 6;
                const float* lp = lds + b * 68 + h8 * 8;
                float4 p0 = *(const float4*)lp, p1 = *(const float4*)(lp + 4);
                f16x8 hi, lo;
                cvt_hilo8(p0, p1, hi, lo);
                const int  k0   = hp * 64 + h8 * 8;
                const long idx2 = ((long)((k0 >> 5) * 4 + (b >> 4)) * 64 + ((b & 15) | (((k0 >> 3) & 3) << 4))) * 8;
                *(f16x8*)(wh_ + idx2) = hi;
                *(f16x8*)(wl_ + idx2) = lo;
            }
            __syncthreads();
            if (tid == 0) {
                __builtin_amdgcn_fence(__ATOMIC_RELEASE, "agent");
                st_flag(flagR + hp, t + 1);
            }
        }
    }
}

// ------------------------------- out GEMM ----------------------------------
// out[row][o] = rate_all[row][:] . Wo[o][:] + bo[o]

__global__ __launch_bounds__(256, 1) void out_gemm(const float* __restrict__ ra,
                                                   const f16* __restrict__ wo,
                                                   const float* __restrict__ bo,
                                                   float* __restrict__ out) {
    const int wg = blockIdx.x, tid = threadIdx.x, wv = tid >> 6, l = tid & 63;
    const int l15 = l & 15, lq = l >> 4;
    const long rowbase = (long)wg * 64;
    f32x4 acc[4] = {{0, 0, 0, 0}, {0, 0, 0, 0}, {0, 0, 0, 0}, {0, 0, 0, 0}};
    const float bov = bo[wv * 16 + l15];
#pragma unroll 4
    for (int kt = 0; kt < 64; ++kt) {
        f16x8 B = *(const f16x8*)(wo + ((long)(wv * 64 + kt) * 64 + l) * 8);
#pragma unroll
        for (int mt = 0; mt < 4; ++mt) {
            const float* ap = ra + (rowbase + mt * 16 + l15) * 2048 + kt * 32 + lq * 8;
            float4 p0 = *(const float4*)ap, p1 = *(const float4*)(ap + 4);
            float v[8] = {p0.x, p0.y, p0.z, p0.w, p1.x, p1.y, p1.z, p1.w};
            f16x8 a;
#pragma unroll
            for (int j = 0; j < 8; ++j) a[j] = (f16)v[j];
            acc[mt] = MFMA16(a, B, acc[mt]);
        }
    }
#pragma unroll
    for (int mt = 0; mt < 4; ++mt)
#pragma unroll
        for (int q = 0; q < 4; ++q)
            out[(rowbase + mt * 16 + lq * 4 + q) * 64 + wv * 16 + l15] = acc[mt][q] + bov;
}

// ------------------------------ launch -------------------------------------

extern "C" void kernel_launch(void* const* d_in, const int* in_sizes, int n_in,
                              void* d_out, int out_size, void* d_ws, size_t ws_size,
                              hipStream_t stream) {
    const float* input = (const float*)d_in[0];
    const float* rate0 = (const float*)d_in[1];
    const float* Wi    = (const float*)d_in[2];
    const float* bi    = (const float*)d_in[3];
    const float* Wh    = (const float*)d_in[4];
    const float* bh    = (const float*)d_in[5];
    const float* Wo    = (const float*)d_in[6];
    const float* bo    = (const float*)d_in[7];

    float* out      = (float*)d_out;
    float* rate_all = out + OUT0_ELEMS;  // pre written here, then overwritten in place

    char* w      = (char*)d_ws;
    int*  flagP  = (int*)(w + WS_FLAGP);
    int*  flagR  = (int*)(w + WS_FLAGR);
    f16*  rs     = (f16*)(w + WS_RSTG);
    f16*  rh0    = rs;
    f16*  rl0    = rs + 131072;
    f16*  rh1    = rs + 262144;
    f16*  rl1    = rs + 393216;
    float* dumps = (float*)(w + WS_DUMP);
    f16*  wi_hi  = (f16*)(w + WS_WI);
    f16*  wi_lo  = wi_hi + 524288;
    f16*  wo_st  = (f16*)(w + WS_WO);

    hipMemsetAsync(d_ws, 0, 4096, stream);  // zero flags every launch
    prep_wi<<<256, 256, 0, stream>>>(Wi, wi_hi, wi_lo);
    prep_wo<<<64, 256, 0, stream>>>(Wo, wo_st);
    prep_r0<<<64, 256, 0, stream>>>(rate0, rh0, rl0);
    pre_gemm<<<4096, 256, 0, stream>>>(input, wi_hi, wi_lo, bi, rate_all);
    scan_kernel<<<256, 256, 0, stream>>>(Wh, bh, rate0, rate_all,
                                         rh0, rl0, rh1, rl1, dumps, flagP, flagR);
    out_gemm<<<512, 256, 0, stream>>>(rate_all, wo_st, bo, out);
}